// Round 1
// baseline (1301.090 us; speedup 1.0000x reference)
//
#include <hip/hip_runtime.h>
#include <hip/hip_bf16.h>
#include <stdint.h>

#define T_LEN 8192
#define NBATCH 8
#define LAYERS 30

typedef __attribute__((ext_vector_type(8))) short bfx8;
typedef __attribute__((ext_vector_type(4))) float fx4;
typedef __attribute__((ext_vector_type(4))) int ix4;

static __device__ __forceinline__ unsigned short f2bf(float f) {
    union { float fv; unsigned u; } v; v.fv = f;
    unsigned r = v.u + 0x7fffu + ((v.u >> 16) & 1u);
    return (unsigned short)(r >> 16);
}

// ---------------------------------------------------------------------------
// Weight packing: fragment-linear bf16 layout.
// Per layer: 88 fragment-blocks of 1KB (64 lanes x 8 bf16).
//   H-GEMM frags f = ks*8+nf, ks in [0,9): ks0-5 conv taps (tap=ks>>1, i=(ks&1)*32+kl),
//     ks6-8 aux (a=(ks-6)*32+kl, zero-pad a>=80).
//   O-GEMM frags f = 72 + ks*8 + nf, ks in [0,2).
// k_local mapping (must match A-side loads): kl = (lane>>4)*8 + j, j=0..7.
// ---------------------------------------------------------------------------
__global__ void pack_weights_k(const float* __restrict__ conv_w,
                               const float* __restrict__ aux_w,
                               const float* __restrict__ out_w,
                               unsigned short* __restrict__ wpack) {
    int tid = blockIdx.x * 256 + threadIdx.x;   // total 30*88*64 = 168960
    int lane = tid & 63;
    int f = (tid >> 6) % 88;
    int l = tid / (88 * 64);
    unsigned short vals[8];
#pragma unroll
    for (int j = 0; j < 8; j++) {
        int kl = ((lane >> 4) * 8) + j;
        float v;
        if (f < 72) {
            int ks = f >> 3, nf = f & 7;
            int g = nf * 16 + (lane & 15);
            if (ks < 6) {
                int tap = ks >> 1;
                int i = (ks & 1) * 32 + kl;
                v = conv_w[((l * 128 + g) * 64 + i) * 3 + tap];
            } else {
                int a = (ks - 6) * 32 + kl;
                v = (a < 80) ? aux_w[(l * 128 + g) * 80 + a] : 0.f;
            }
        } else {
            int fo = f - 72;
            int ks = fo >> 3, nf = fo & 7;
            int p = nf * 16 + (lane & 15);
            v = out_w[(l * 128 + p) * 64 + ks * 32 + kl];
        }
        vals[j] = f2bf(v);
    }
    unsigned* dst = (unsigned*)(wpack + (size_t)tid * 8);
    dst[0] = (unsigned)vals[0] | ((unsigned)vals[1] << 16);
    dst[1] = (unsigned)vals[2] | ((unsigned)vals[3] << 16);
    dst[2] = (unsigned)vals[4] | ((unsigned)vals[5] << 16);
    dst[3] = (unsigned)vals[6] | ((unsigned)vals[7] << 16);
}

// c (B,80,T) f32  ->  cbf (B,T,96) bf16, zero-padded channels 80..95
__global__ void prep_c_k(const float* __restrict__ c, unsigned short* __restrict__ cbf) {
    __shared__ float tile[80][65];
    int bid = blockIdx.x;                 // B * 128 tiles
    int b = bid >> 7;
    int t0 = (bid & 127) << 6;
    for (int idx = threadIdx.x; idx < 80 * 64; idx += 256) {
        int a = idx >> 6, tt = idx & 63;
        tile[a][tt] = c[((size_t)(b * 80 + a)) * T_LEN + t0 + tt];
    }
    __syncthreads();
    for (int idx = threadIdx.x; idx < 64 * 96; idx += 256) {
        int tt = idx / 96, a = idx % 96;
        float v = (a < 80) ? tile[a][tt] : 0.f;
        cbf[((size_t)(b * T_LEN + t0 + tt)) * 96 + a] = f2bf(v);
    }
}

// first 1x1 conv -> xf32 (B,T,64) + xbfA (B,T,64);  also zero skip (B,T,64) f32
__global__ void first_init_k(const float* __restrict__ x,
                             const float* __restrict__ fw, const float* __restrict__ fb,
                             float* __restrict__ xf32, unsigned short* __restrict__ xbf,
                             float* __restrict__ skip) {
    int vi = blockIdx.x * 256 + threadIdx.x;   // 2 * 1048576 total
    if (vi < 1048576) {
        int pos = vi >> 4;
        int rc = (vi & 15) * 4;
        float xs = x[pos];
        const float4 w = *(const float4*)(fw + rc);
        const float4 bb = *(const float4*)(fb + rc);
        float4 val = make_float4(w.x * xs + bb.x, w.y * xs + bb.y,
                                 w.z * xs + bb.z, w.w * xs + bb.w);
        *(float4*)(xf32 + (((size_t)pos) << 6) + rc) = val;
        unsigned* dst = (unsigned*)(xbf + (((size_t)pos) << 6) + rc);
        dst[0] = (unsigned)f2bf(val.x) | ((unsigned)f2bf(val.y) << 16);
        dst[1] = (unsigned)f2bf(val.z) | ((unsigned)f2bf(val.w) << 16);
    } else {
        int si = vi - 1048576;
        float4 z = make_float4(0.f, 0.f, 0.f, 0.f);
        *(float4*)(skip + (size_t)si * 4) = z;
    }
}

// ---------------------------------------------------------------------------
// Fused layer: dilated conv + aux + gate + out 1x1 + residual + skip.
// Block: 256 threads (4 waves), tile = 64 t x 128 out-ch, wave w owns ch [32w,32w+32).
// ---------------------------------------------------------------------------
__global__ __launch_bounds__(256) void layer_k(
    const unsigned short* __restrict__ xbf_cur,
    unsigned short* __restrict__ xbf_next,
    float* __restrict__ xf32,
    float* __restrict__ skip,
    const unsigned short* __restrict__ cbf,
    const float* __restrict__ xmask,
    const unsigned short* __restrict__ wl,
    const float* __restrict__ conv_b_l,
    const float* __restrict__ out_b_l,
    int d)
{
    __shared__ char smem[43264];
    unsigned short* xtap  = (unsigned short*)smem;            // [3][64][72] bf16 (27648 B)
    unsigned short* ctile = (unsigned short*)(smem + 27648);  // [64][104]  bf16 (13312 B)
    float*          h_lds = (float*)smem;                     // [64][132]  f32  (33792 B) overlays stage
    unsigned short* z_lds = (unsigned short*)(smem + 33792);  // [64][72]   bf16 ( 9216 B)
    float*       mask_lds = (float*)(smem + 43008);           // [64] f32

    const int tid = threadIdx.x;
    const int lane = tid & 63;
    const int wv = tid >> 6;
    const int bid = blockIdx.x;
    const int b = bid >> 7;
    const int t0 = (bid & 127) << 6;
    const long rowbase = (long)b * T_LEN;

    // ---------- stage x taps (bf16), c tile, mask ----------
    for (int idx = tid; idx < 1536; idx += 256) {
        int tap = idx >> 9;
        int rem = idx & 511;
        int row = rem >> 3;
        int seg = rem & 7;
        int tg = t0 + row + (tap - 1) * d;
        ix4 v = {0, 0, 0, 0};
        if ((unsigned)tg < (unsigned)T_LEN)
            v = *(const ix4*)(xbf_cur + ((rowbase + tg) << 6) + seg * 8);
        *(ix4*)(xtap + (tap * 64 + row) * 72 + seg * 8) = v;
    }
    for (int idx = tid; idx < 768; idx += 256) {
        int row = idx / 12;
        int seg = idx % 12;
        ix4 v = *(const ix4*)(cbf + (rowbase + t0 + row) * 96 + seg * 8);
        *(ix4*)(ctile + row * 104 + seg * 8) = v;
    }
    if (tid < 64) mask_lds[tid] = xmask[rowbase + t0 + tid];
    __syncthreads();

    const int klane = (lane >> 4) * 8;
    const int mrow = lane & 15;

    // ---------- H GEMM: K = 3*64 (conv taps) + 96 (aux, padded) ----------
    fx4 acc[4][2];
#pragma unroll
    for (int m = 0; m < 4; m++) {
        acc[m][0] = (fx4){0.f, 0.f, 0.f, 0.f};
        acc[m][1] = (fx4){0.f, 0.f, 0.f, 0.f};
    }
    for (int ks = 0; ks < 9; ks++) {
        const unsigned short* abase;
        int off, stride;
        if (ks < 6) { abase = xtap + (ks >> 1) * (64 * 72); off = (ks & 1) * 32; stride = 72; }
        else        { abase = ctile;                        off = (ks - 6) * 32; stride = 104; }
        bfx8 af[4];
#pragma unroll
        for (int m = 0; m < 4; m++)
            af[m] = *(const bfx8*)(abase + (m * 16 + mrow) * stride + off + klane);
        bfx8 bfr[2];
#pragma unroll
        for (int n = 0; n < 2; n++)
            bfr[n] = *(const bfx8*)(wl + (size_t)((ks * 8 + (wv * 2 + n)) * 64 + lane) * 8);
#pragma unroll
        for (int m = 0; m < 4; m++)
#pragma unroll
            for (int n = 0; n < 2; n++)
                acc[m][n] = __builtin_amdgcn_mfma_f32_16x16x32_bf16(af[m], bfr[n], acc[m][n], 0, 0, 0);
    }
    __syncthreads();   // stage buffers dead; safe to overlay h_lds

    // bias + write h to LDS
#pragma unroll
    for (int n = 0; n < 2; n++) {
        int g = wv * 32 + n * 16 + mrow;
        float cb = conv_b_l[g];
#pragma unroll
        for (int m = 0; m < 4; m++)
#pragma unroll
            for (int r = 0; r < 4; r++)
                h_lds[(m * 16 + (lane >> 4) * 4 + r) * 132 + g] = acc[m][n][r] + cb;
    }
    __syncthreads();

    // ---------- gate: z = tanh(h[:64]) * sigmoid(h[64:]) ----------
    for (int idx = tid; idx < 4096; idx += 256) {
        int t = idx >> 6, j = idx & 63;
        float xa = h_lds[t * 132 + j];
        float xb = h_lds[t * 132 + 64 + j];
        float e2 = __expf(2.f * xa);
        float th = 1.f - 2.f / (e2 + 1.f);
        float sg = 1.f / (1.f + __expf(-xb));
        z_lds[t * 72 + j] = f2bf(th * sg);
    }
    __syncthreads();

    // ---------- O GEMM: K = 64 ----------
    fx4 acc2[4][2];
#pragma unroll
    for (int m = 0; m < 4; m++) {
        acc2[m][0] = (fx4){0.f, 0.f, 0.f, 0.f};
        acc2[m][1] = (fx4){0.f, 0.f, 0.f, 0.f};
    }
    for (int ks = 0; ks < 2; ks++) {
        bfx8 af[4];
#pragma unroll
        for (int m = 0; m < 4; m++)
            af[m] = *(const bfx8*)(z_lds + (m * 16 + mrow) * 72 + ks * 32 + klane);
        bfx8 bfr[2];
#pragma unroll
        for (int n = 0; n < 2; n++)
            bfr[n] = *(const bfx8*)(wl + (size_t)(((72 + ks * 8) + (wv * 2 + n)) * 64 + lane) * 8);
#pragma unroll
        for (int m = 0; m < 4; m++)
#pragma unroll
            for (int n = 0; n < 2; n++)
                acc2[m][n] = __builtin_amdgcn_mfma_f32_16x16x32_bf16(af[m], bfr[n], acc2[m][n], 0, 0, 0);
    }

    // ---------- epilogue: bias, mask, residual (waves 0-1) / skip (waves 2-3) ----------
#pragma unroll
    for (int n = 0; n < 2; n++) {
        int p = wv * 32 + n * 16 + mrow;
        float ob = out_b_l[p];
#pragma unroll
        for (int m = 0; m < 4; m++)
#pragma unroll
            for (int r = 0; r < 4; r++) {
                int t = m * 16 + (lane >> 4) * 4 + r;
                float val = (acc2[m][n][r] + ob) * mask_lds[t];
                long ro = (rowbase + t0 + t) << 6;
                if (wv < 2) {
                    float nx = xf32[ro + p] + val;
                    xf32[ro + p] = nx;
                    xbf_next[ro + p] = f2bf(nx);
                } else {
                    skip[ro + (p - 64)] += val;
                }
            }
    }
}

// last_conv: relu -> 1x1(64x64) -> relu -> 1x1(1x64)
__global__ void final_k(const float* __restrict__ skip,
                        const float* __restrict__ w1, const float* __restrict__ b1,
                        const float* __restrict__ w2, const float* __restrict__ b2,
                        float* __restrict__ out) {
    int pos = blockIdx.x * 256 + threadIdx.x;  // 65536 total
    const float* row = skip + (size_t)pos * 64;
    float acc[64];
#pragma unroll
    for (int o = 0; o < 64; o++) acc[o] = b1[o];
    for (int j = 0; j < 64; j += 4) {
        float4 v = *(const float4*)(row + j);
        float s0 = fmaxf(v.x, 0.f), s1 = fmaxf(v.y, 0.f);
        float s2 = fmaxf(v.z, 0.f), s3 = fmaxf(v.w, 0.f);
#pragma unroll
        for (int o = 0; o < 64; o++) {
            acc[o] += w1[o * 64 + j] * s0 + w1[o * 64 + j + 1] * s1
                    + w1[o * 64 + j + 2] * s2 + w1[o * 64 + j + 3] * s3;
        }
    }
    float s = b2[0];
#pragma unroll
    for (int o = 0; o < 64; o++) s += w2[o] * fmaxf(acc[o], 0.f);
    out[pos] = s;
}

extern "C" void kernel_launch(void* const* d_in, const int* in_sizes, int n_in,
                              void* d_out, int out_size, void* d_ws, size_t ws_size,
                              hipStream_t stream) {
    const float* x       = (const float*)d_in[0];
    const float* xmask   = (const float*)d_in[1];
    const float* c       = (const float*)d_in[2];
    const float* first_w = (const float*)d_in[3];
    const float* first_b = (const float*)d_in[4];
    const float* conv_w  = (const float*)d_in[5];
    const float* conv_b  = (const float*)d_in[6];
    const float* aux_w   = (const float*)d_in[7];
    const float* out_w   = (const float*)d_in[8];
    const float* out_b   = (const float*)d_in[9];
    const float* lw1     = (const float*)d_in[10];
    const float* lb1     = (const float*)d_in[11];
    const float* lw2     = (const float*)d_in[12];
    const float* lb2     = (const float*)d_in[13];
    float* out = (float*)d_out;

    char* ws = (char*)d_ws;
    float*          xf32  = (float*)(ws + 0);                   // 16,777,216 B
    unsigned short* xbfA  = (unsigned short*)(ws + 16777216);   //  8,388,608 B
    unsigned short* xbfB  = (unsigned short*)(ws + 25165824);   //  8,388,608 B
    float*          skip  = (float*)(ws + 33554432);            // 16,777,216 B
    unsigned short* cbf   = (unsigned short*)(ws + 50331648);   // 12,582,912 B
    unsigned short* wpack = (unsigned short*)(ws + 62914560);   //  2,703,360 B  (end 65,617,920)

    pack_weights_k<<<660, 256, 0, stream>>>(conv_w, aux_w, out_w, wpack);
    prep_c_k<<<1024, 256, 0, stream>>>(c, cbf);
    first_init_k<<<8192, 256, 0, stream>>>(x, first_w, first_b, xf32, xbfA, skip);

    const unsigned short* cur = xbfA;
    unsigned short* nxt = xbfB;
    for (int l = 0; l < LAYERS; l++) {
        int d = 1 << (l % 10);
        layer_k<<<1024, 256, 0, stream>>>(cur, nxt, xf32, skip, cbf, xmask,
                                          wpack + (size_t)l * 45056,
                                          conv_b + l * 128, out_b + l * 128, d);
        const unsigned short* tmp = nxt;
        nxt = (unsigned short*)cur;
        cur = tmp;
    }
    final_k<<<256, 256, 0, stream>>>(skip, lw1, lb1, lw2, lb2, out);
}

// Round 2
// 1118.867 us; speedup vs baseline: 1.1629x; 1.1629x over previous
//
#include <hip/hip_runtime.h>
#include <hip/hip_bf16.h>
#include <stdint.h>

#define T_LEN 8192
#define NBATCH 8
#define LAYERS 30

typedef __attribute__((ext_vector_type(8))) short bfx8;
typedef __attribute__((ext_vector_type(4))) float fx4;
typedef __attribute__((ext_vector_type(4))) int ix4;

static __device__ __forceinline__ unsigned short f2bf(float f) {
    union { float fv; unsigned u; } v; v.fv = f;
    unsigned r = v.u + 0x7fffu + ((v.u >> 16) & 1u);
    return (unsigned short)(r >> 16);
}

// ---------------------------------------------------------------------------
// Weight packing: fragment-linear bf16 layout (see R0 notes).
// Per layer: 88 fragment-blocks of 1KB (64 lanes x 8 bf16).
// k_local mapping matches A-side loads: kl = (lane>>4)*8 + j.
// ---------------------------------------------------------------------------
__global__ void pack_weights_k(const float* __restrict__ conv_w,
                               const float* __restrict__ aux_w,
                               const float* __restrict__ out_w,
                               unsigned short* __restrict__ wpack) {
    int tid = blockIdx.x * 256 + threadIdx.x;   // total 30*88*64 = 168960
    int lane = tid & 63;
    int f = (tid >> 6) % 88;
    int l = tid / (88 * 64);
    unsigned short vals[8];
#pragma unroll
    for (int j = 0; j < 8; j++) {
        int kl = ((lane >> 4) * 8) + j;
        float v;
        if (f < 72) {
            int ks = f >> 3, nf = f & 7;
            int g = nf * 16 + (lane & 15);
            if (ks < 6) {
                int tap = ks >> 1;
                int i = (ks & 1) * 32 + kl;
                v = conv_w[((l * 128 + g) * 64 + i) * 3 + tap];
            } else {
                int a = (ks - 6) * 32 + kl;
                v = (a < 80) ? aux_w[(l * 128 + g) * 80 + a] : 0.f;
            }
        } else {
            int fo = f - 72;
            int ks = fo >> 3, nf = fo & 7;
            int p = nf * 16 + (lane & 15);
            v = out_w[(l * 128 + p) * 64 + ks * 32 + kl];
        }
        vals[j] = f2bf(v);
    }
    unsigned* dst = (unsigned*)(wpack + (size_t)tid * 8);
    dst[0] = (unsigned)vals[0] | ((unsigned)vals[1] << 16);
    dst[1] = (unsigned)vals[2] | ((unsigned)vals[3] << 16);
    dst[2] = (unsigned)vals[4] | ((unsigned)vals[5] << 16);
    dst[3] = (unsigned)vals[6] | ((unsigned)vals[7] << 16);
}

// c (B,80,T) f32  ->  cbf (B,T,96) bf16, zero-padded channels 80..95
__global__ void prep_c_k(const float* __restrict__ c, unsigned short* __restrict__ cbf) {
    __shared__ float tile[80][65];
    int bid = blockIdx.x;                 // B * 128 tiles
    int b = bid >> 7;
    int t0 = (bid & 127) << 6;
    for (int idx = threadIdx.x; idx < 80 * 64; idx += 256) {
        int a = idx >> 6, tt = idx & 63;
        tile[a][tt] = c[((size_t)(b * 80 + a)) * T_LEN + t0 + tt];
    }
    __syncthreads();
    for (int idx = threadIdx.x; idx < 64 * 96; idx += 256) {
        int tt = idx / 96, a = idx % 96;
        float v = (a < 80) ? tile[a][tt] : 0.f;
        cbf[((size_t)(b * T_LEN + t0 + tt)) * 96 + a] = f2bf(v);
    }
}

// first 1x1 conv -> xf32 (B,T,64) + xbfA (B,T,64);  also zero skip (B,T,64) f32
__global__ void first_init_k(const float* __restrict__ x,
                             const float* __restrict__ fw, const float* __restrict__ fb,
                             float* __restrict__ xf32, unsigned short* __restrict__ xbf,
                             float* __restrict__ skip) {
    int vi = blockIdx.x * 256 + threadIdx.x;   // 2 * 1048576 total
    if (vi < 1048576) {
        int pos = vi >> 4;
        int rc = (vi & 15) * 4;
        float xs = x[pos];
        const float4 w = *(const float4*)(fw + rc);
        const float4 bb = *(const float4*)(fb + rc);
        float4 val = make_float4(w.x * xs + bb.x, w.y * xs + bb.y,
                                 w.z * xs + bb.z, w.w * xs + bb.w);
        *(float4*)(xf32 + (((size_t)pos) << 6) + rc) = val;
        unsigned* dst = (unsigned*)(xbf + (((size_t)pos) << 6) + rc);
        dst[0] = (unsigned)f2bf(val.x) | ((unsigned)f2bf(val.y) << 16);
        dst[1] = (unsigned)f2bf(val.z) | ((unsigned)f2bf(val.w) << 16);
    } else {
        int si = vi - 1048576;
        float4 z = make_float4(0.f, 0.f, 0.f, 0.f);
        *(float4*)(skip + (size_t)si * 4) = z;
    }
}

// ---------------------------------------------------------------------------
// Fused layer: dilated conv + aux + gate + out 1x1 + residual + skip.
// Block: 256 threads (4 waves), tile = 64 t x 128 out-ch, wave w owns ch [32w,32w+32).
// XCD-chunked swizzle: 1024 blocks = 8 XCDs x 128 tiles -> XCD k owns batch k
// (dilated-tap halos stay in that XCD's L2).
// ---------------------------------------------------------------------------
__global__ __launch_bounds__(256) void layer_k(
    const unsigned short* __restrict__ xbf_cur,
    unsigned short* __restrict__ xbf_next,
    float* __restrict__ xf32,
    float* __restrict__ skip,
    const unsigned short* __restrict__ cbf,
    const float* __restrict__ xmask,
    const unsigned short* __restrict__ wl,
    const float* __restrict__ conv_b_l,
    const float* __restrict__ out_b_l,
    int d)
{
    __shared__ char smem[43264];
    unsigned short* xtap  = (unsigned short*)smem;            // [3][64][72] bf16 (27648 B)
    unsigned short* ctile = (unsigned short*)(smem + 27648);  // [64][104]  bf16 (13312 B)
    float*          h_lds = (float*)smem;                     // [64][132]  f32  (33792 B) overlays stage
    unsigned short* z_lds = (unsigned short*)(smem + 33792);  // [64][72]   bf16 ( 9216 B)
    float*       mask_lds = (float*)(smem + 43008);           // [64] f32

    const int tid = threadIdx.x;
    const int lane = tid & 63;
    const int wv = tid >> 6;
    int bid = blockIdx.x;
    bid = (bid & 7) * 128 + (bid >> 3);   // XCD-chunked (1024 % 8 == 0, bijective)
    const int b = bid >> 7;
    const int t0 = (bid & 127) << 6;
    const long rowbase = (long)b * T_LEN;

    // ---------- stage x taps (bf16), c tile, mask ----------
    for (int idx = tid; idx < 1536; idx += 256) {
        int tap = idx >> 9;
        int rem = idx & 511;
        int row = rem >> 3;
        int seg = rem & 7;
        int tg = t0 + row + (tap - 1) * d;
        ix4 v = {0, 0, 0, 0};
        if ((unsigned)tg < (unsigned)T_LEN)
            v = *(const ix4*)(xbf_cur + ((rowbase + tg) << 6) + seg * 8);
        *(ix4*)(xtap + (tap * 64 + row) * 72 + seg * 8) = v;
    }
    for (int idx = tid; idx < 768; idx += 256) {
        int row = idx / 12;
        int seg = idx % 12;
        ix4 v = *(const ix4*)(cbf + (rowbase + t0 + row) * 96 + seg * 8);
        *(ix4*)(ctile + row * 104 + seg * 8) = v;
    }
    if (tid < 64) mask_lds[tid] = xmask[rowbase + t0 + tid];
    __syncthreads();

    const int klane = (lane >> 4) * 8;
    const int mrow = lane & 15;

    // ---------- H GEMM: K = 3*64 (conv taps) + 96 (aux, padded) ----------
    fx4 acc[4][2];
#pragma unroll
    for (int m = 0; m < 4; m++) {
        acc[m][0] = (fx4){0.f, 0.f, 0.f, 0.f};
        acc[m][1] = (fx4){0.f, 0.f, 0.f, 0.f};
    }
    for (int ks = 0; ks < 9; ks++) {
        const unsigned short* abase;
        int off, stride;
        if (ks < 6) { abase = xtap + (ks >> 1) * (64 * 72); off = (ks & 1) * 32; stride = 72; }
        else        { abase = ctile;                        off = (ks - 6) * 32; stride = 104; }
        bfx8 af[4];
#pragma unroll
        for (int m = 0; m < 4; m++)
            af[m] = *(const bfx8*)(abase + (m * 16 + mrow) * stride + off + klane);
        bfx8 bfr[2];
#pragma unroll
        for (int n = 0; n < 2; n++)
            bfr[n] = *(const bfx8*)(wl + (size_t)((ks * 8 + (wv * 2 + n)) * 64 + lane) * 8);
#pragma unroll
        for (int m = 0; m < 4; m++)
#pragma unroll
            for (int n = 0; n < 2; n++)
                acc[m][n] = __builtin_amdgcn_mfma_f32_16x16x32_bf16(af[m], bfr[n], acc[m][n], 0, 0, 0);
    }
    __syncthreads();   // stage buffers dead; safe to overlay h_lds

    // bias + write h to LDS
#pragma unroll
    for (int n = 0; n < 2; n++) {
        int g = wv * 32 + n * 16 + mrow;
        float cb = conv_b_l[g];
#pragma unroll
        for (int m = 0; m < 4; m++)
#pragma unroll
            for (int r = 0; r < 4; r++)
                h_lds[(m * 16 + (lane >> 4) * 4 + r) * 132 + g] = acc[m][n][r] + cb;
    }
    __syncthreads();

    // ---------- gate: z = tanh(h[:64]) * sigmoid(h[64:]) ----------
    for (int idx = tid; idx < 4096; idx += 256) {
        int t = idx >> 6, j = idx & 63;
        float xa = h_lds[t * 132 + j];
        float xb = h_lds[t * 132 + 64 + j];
        float e2 = __expf(2.f * xa);
        float th = 1.f - 2.f / (e2 + 1.f);
        float sg = 1.f / (1.f + __expf(-xb));
        z_lds[t * 72 + j] = f2bf(th * sg);
    }
    __syncthreads();

    // ---------- O GEMM: K = 64 ----------
    fx4 acc2[4][2];
#pragma unroll
    for (int m = 0; m < 4; m++) {
        acc2[m][0] = (fx4){0.f, 0.f, 0.f, 0.f};
        acc2[m][1] = (fx4){0.f, 0.f, 0.f, 0.f};
    }
    for (int ks = 0; ks < 2; ks++) {
        bfx8 af[4];
#pragma unroll
        for (int m = 0; m < 4; m++)
            af[m] = *(const bfx8*)(z_lds + (m * 16 + mrow) * 72 + ks * 32 + klane);
        bfx8 bfr[2];
#pragma unroll
        for (int n = 0; n < 2; n++)
            bfr[n] = *(const bfx8*)(wl + (size_t)(((72 + ks * 8) + (wv * 2 + n)) * 64 + lane) * 8);
#pragma unroll
        for (int m = 0; m < 4; m++)
#pragma unroll
            for (int n = 0; n < 2; n++)
                acc2[m][n] = __builtin_amdgcn_mfma_f32_16x16x32_bf16(af[m], bfr[n], acc2[m][n], 0, 0, 0);
    }

    // ---------- epilogue: transpose o through LDS, then vectorized RMW ----------
    // write biased+masked o to h_lds[t][p] (h region dead after gate; z not overlapped)
#pragma unroll
    for (int n = 0; n < 2; n++) {
        int p = wv * 32 + n * 16 + mrow;
        float ob = out_b_l[p];
#pragma unroll
        for (int m = 0; m < 4; m++)
#pragma unroll
            for (int r = 0; r < 4; r++) {
                int t = m * 16 + (lane >> 4) * 4 + r;
                h_lds[t * 132 + p] = (acc2[m][n][r] + ob) * mask_lds[t];
            }
    }
    __syncthreads();

    {
        int t = tid >> 2;          // 64 rows x 4 threads
        int q = tid & 3;           // q 0-1: residual ch [32q,32q+32); q 2-3: skip ch [32(q-2),..)
        const float* src = h_lds + t * 132 + q * 32;
        long ro = (rowbase + t0 + t) << 6;
        if (q < 2) {
            float* xp = xf32 + ro + q * 32;
            unsigned short* bp = xbf_next + ro + q * 32;
            unsigned pk[16];
#pragma unroll
            for (int k = 0; k < 8; k++) {
                float4 o4 = *(const float4*)(src + k * 4);
                float4 xv = *(float4*)(xp + k * 4);
                xv.x += o4.x; xv.y += o4.y; xv.z += o4.z; xv.w += o4.w;
                *(float4*)(xp + k * 4) = xv;
                pk[k * 2]     = (unsigned)f2bf(xv.x) | ((unsigned)f2bf(xv.y) << 16);
                pk[k * 2 + 1] = (unsigned)f2bf(xv.z) | ((unsigned)f2bf(xv.w) << 16);
            }
#pragma unroll
            for (int k = 0; k < 4; k++)
                *(ix4*)(bp + k * 8) = *(const ix4*)(pk + k * 4);
        } else {
            float* sp = skip + ro + (q - 2) * 32;
#pragma unroll
            for (int k = 0; k < 8; k++) {
                float4 o4 = *(const float4*)(src + k * 4);
                float4 sv = *(float4*)(sp + k * 4);
                sv.x += o4.x; sv.y += o4.y; sv.z += o4.z; sv.w += o4.w;
                *(float4*)(sp + k * 4) = sv;
            }
        }
    }
}

// last_conv: relu -> 1x1(64x64) -> relu -> 1x1(1x64)
// w1 staged in LDS (broadcast reads), skip row in registers, scalar o-loop
// (no 64-deep accumulator array -> no spill).
__global__ __launch_bounds__(256) void final_k(
        const float* __restrict__ skip,
        const float* __restrict__ w1, const float* __restrict__ b1,
        const float* __restrict__ w2, const float* __restrict__ b2,
        float* __restrict__ out) {
    __shared__ float w1s[4096];
    __shared__ float b1s[64];
    __shared__ float w2s[64];
    for (int i = threadIdx.x; i < 4096; i += 256) w1s[i] = w1[i];
    if (threadIdx.x < 64) {
        b1s[threadIdx.x] = b1[threadIdx.x];
        w2s[threadIdx.x] = w2[threadIdx.x];
    }
    __syncthreads();

    int pos = blockIdx.x * 256 + threadIdx.x;   // 65536 total
    const float4* row = (const float4*)(skip + (size_t)pos * 64);
    float4 s[16];
#pragma unroll
    for (int j = 0; j < 16; j++) {
        float4 v = row[j];
        s[j] = make_float4(fmaxf(v.x, 0.f), fmaxf(v.y, 0.f),
                           fmaxf(v.z, 0.f), fmaxf(v.w, 0.f));
    }
    float total = b2[0];
    for (int o = 0; o < 64; o++) {
        const float4* wr = (const float4*)(w1s + o * 64);
        float d0 = 0.f, d1 = 0.f, d2 = 0.f, d3 = 0.f;
#pragma unroll
        for (int j = 0; j < 16; j++) {
            float4 w = wr[j];
            d0 = fmaf(w.x, s[j].x, d0);
            d1 = fmaf(w.y, s[j].y, d1);
            d2 = fmaf(w.z, s[j].z, d2);
            d3 = fmaf(w.w, s[j].w, d3);
        }
        float dot = (d0 + d1) + (d2 + d3) + b1s[o];
        total = fmaf(w2s[o], fmaxf(dot, 0.f), total);
    }
    out[pos] = total;
}

extern "C" void kernel_launch(void* const* d_in, const int* in_sizes, int n_in,
                              void* d_out, int out_size, void* d_ws, size_t ws_size,
                              hipStream_t stream) {
    const float* x       = (const float*)d_in[0];
    const float* xmask   = (const float*)d_in[1];
    const float* c       = (const float*)d_in[2];
    const float* first_w = (const float*)d_in[3];
    const float* first_b = (const float*)d_in[4];
    const float* conv_w  = (const float*)d_in[5];
    const float* conv_b  = (const float*)d_in[6];
    const float* aux_w   = (const float*)d_in[7];
    const float* out_w   = (const float*)d_in[8];
    const float* out_b   = (const float*)d_in[9];
    const float* lw1     = (const float*)d_in[10];
    const float* lb1     = (const float*)d_in[11];
    const float* lw2     = (const float*)d_in[12];
    const float* lb2     = (const float*)d_in[13];
    float* out = (float*)d_out;

    char* ws = (char*)d_ws;
    float*          xf32  = (float*)(ws + 0);                   // 16,777,216 B
    unsigned short* xbfA  = (unsigned short*)(ws + 16777216);   //  8,388,608 B
    unsigned short* xbfB  = (unsigned short*)(ws + 25165824);   //  8,388,608 B
    float*          skip  = (float*)(ws + 33554432);            // 16,777,216 B
    unsigned short* cbf   = (unsigned short*)(ws + 50331648);   // 12,582,912 B
    unsigned short* wpack = (unsigned short*)(ws + 62914560);   //  2,703,360 B  (end 65,617,920)

    pack_weights_k<<<660, 256, 0, stream>>>(conv_w, aux_w, out_w, wpack);
    prep_c_k<<<1024, 256, 0, stream>>>(c, cbf);
    first_init_k<<<8192, 256, 0, stream>>>(x, first_w, first_b, xf32, xbfA, skip);

    const unsigned short* cur = xbfA;
    unsigned short* nxt = xbfB;
    for (int l = 0; l < LAYERS; l++) {
        int d = 1 << (l % 10);
        layer_k<<<1024, 256, 0, stream>>>(cur, nxt, xf32, skip, cbf, xmask,
                                          wpack + (size_t)l * 45056,
                                          conv_b + l * 128, out_b + l * 128, d);
        const unsigned short* tmp = nxt;
        nxt = (unsigned short*)cur;
        cur = tmp;
    }
    final_k<<<256, 256, 0, stream>>>(skip, lw1, lb1, lw2, lb2, out);
}